// Round 9
// baseline (56.006 us; speedup 1.0000x reference)
//
#include <hip/hip_runtime.h>
#include <math.h>

namespace {
typedef float v2f __attribute__((ext_vector_type(2)));

constexpr int B = 16, CH = 4, H = 512, W = 512, HID = 8;
constexpr int STRIP  = 16;           // rows per block
constexpr int SLOT_F = CH * W;       // one full row, all channels = 8 KB
constexpr int NSLOT  = 8;            // 64 KB ring -> 2 blocks/CU

static __device__ __forceinline__ v2f splat(float f){ v2f r; r.x=f; r.y=f; return r; }

// Block = 256 thr = 4 waves. Per step: 2 rows; wave wv -> row hs+2k+(wv>>1),
// columns [(wv&1)*256, +255], 4 px/thread. Halos via in-wave shuffle of column
// sums; the 2 wave-boundary lanes read their halo column straight from LDS.
// Ring prefetched 2 steps ahead with counted vmcnt (never drained mid-loop).
__global__ __launch_bounds__(256) void ca_kernel(
    const float* __restrict__ x,      // [16,4,512,512]
    const float* __restrict__ w1w,    // [8,16]
    const float* __restrict__ w1b,    // [8]
    const float* __restrict__ w2w,    // [4,8]
    const float* __restrict__ noise,  // [16,1,512,512]
    float* __restrict__ out)          // [16,4,512,512]
{
    __shared__ float smem[NSLOT * SLOT_F];

    const int blk  = blockIdx.x;             // 512 blocks
    const int b    = blk >> 5;               // image
    const int hs   = (blk & 31) * STRIP;     // strip start row
    const int tid  = threadIdx.x;
    const int wv   = tid >> 6;               // wave 0..3
    const int lane = tid & 63;
    const int rsel = wv >> 1;                // which of the step's 2 rows
    const int part = wv & 1;                 // which half of the row
    const int w0   = part * 256 + lane * 4;  // 4 consecutive columns
    const bool ln0  = (lane == 0);
    const bool ln63 = (lane == 63);
    const int hcol = ln0 ? ((w0 - 1) & (W - 1)) : ((w0 + 4) & (W - 1));
    const int lm1  = (lane + 63) & 63;
    const int lp1  = (lane + 1) & 63;

    const float* xb = x + (size_t)b * CH * H * W;

    // stage rows q, q+1: wave wv stages channel wv (2 x 1KB chunks per row)
    auto dma2 = [&](int q) {
#pragma unroll
        for (int r2 = 0; r2 < 2; ++r2) {
            const int row  = (q + r2) & (H - 1);
            const int slot = (q + r2 - hs + 1) & (NSLOT - 1);
#pragma unroll
            for (int hf = 0; hf < 2; ++hf) {
                const float* g = xb + ((size_t)wv * H + row) * W + hf * 256 + lane * 4;
                const float* l = &smem[slot * SLOT_F + wv * W + hf * 256]; // wave-uniform
                __builtin_amdgcn_global_load_lds(
                    (const __attribute__((address_space(1))) void*)g,
                    (__attribute__((address_space(3))) void*)l, 16, 0, 0);
            }
        }
    };

    // prologue: windows(0)+(1) = rows hs-1 .. hs+4, then noise for step 0
    dma2(hs - 1); dma2(hs + 1); dma2(hs + 3);
    const float* nbase = noise + (size_t)b * H * W;
    float4 nz = *(const float4*)&nbase[(size_t)(hs + rsel) * W + w0];
    float4 nz_next;

#pragma unroll
    for (int k = 0; k < 8; ++k) {
        // entry wait: all but the newest 8 VMEM ops (prev step's 4 dma + 4
        // stores) complete => window(k)'s dma (issued 2 steps ago) landed.
        if (k == 0) asm volatile("s_waitcnt vmcnt(0)" ::: "memory");
        else        asm volatile("s_waitcnt vmcnt(8)" ::: "memory");
        __builtin_amdgcn_s_barrier();

        const int r = hs + 2 * k + rsel;
        // noise prefetch FIRST (in-order vmcnt: its completion-wait next step
        // must not force this step's dma batch to drain)
        if (k < 7) nz_next = *(const float4*)&nbase[(size_t)((r + 2) & (H - 1)) * W + w0];
        if (k < 6) dma2(hs + 2 * k + 5);     // window(k+2)'s two new rows

        const int sT = (2 * k + rsel)     & 7;
        const int sM = (2 * k + rsel + 1) & 7;
        const int sB = (2 * k + rsel + 2) & 7;

        v2f hpre[HID][2];
#pragma unroll
        for (int o = 0; o < HID; ++o) {
            const v2f bo = splat(w1b[o]);
            hpre[o][0] = bo; hpre[o][1] = bo;
        }
        v2f xcv[CH][2];

#pragma unroll
        for (int ch = 0; ch < CH; ++ch) {
            const float* T  = &smem[sT * SLOT_F + ch * W];
            const float* M  = &smem[sM * SLOT_F + ch * W];
            const float* Bt = &smem[sB * SLOT_F + ch * W];
            // stride-16B sequential b128 reads: conflict-free
            const float4 t4 = *(const float4*)&T[w0];
            const float4 m4 = *(const float4*)&M[w0];
            const float4 b4 = *(const float4*)&Bt[w0];
            // wave-boundary halo: 2 lanes read their halo column from LDS
            float sh = 0.f, dh = 0.f;
            if (ln0 || ln63) {
                const float th = T[hcol], mh = M[hcol], bh = Bt[hcol];
                sh = fmaf(2.f, mh, th + bh);
                dh = bh - th;
            }

            const float tt[4] = { t4.x, t4.y, t4.z, t4.w };
            const float mm[4] = { m4.x, m4.y, m4.z, m4.w };
            const float bb[4] = { b4.x, b4.y, b4.z, b4.w };
            float s[4], d[4];
#pragma unroll
            for (int j = 0; j < 4; ++j) {
                s[j] = fmaf(2.f, mm[j], tt[j] + bb[j]);
                d[j] = bb[j] - tt[j];
            }

            float sl = __shfl(s[3], lm1, 64); if (ln0)  sl = sh;
            float sr = __shfl(s[0], lp1, 64); if (ln63) sr = sh;
            float dl = __shfl(d[3], lm1, 64); if (ln0)  dl = dh;
            float dr = __shfl(d[0], lp1, 64); if (ln63) dr = dh;

            const float se[6] = { sl, s[0], s[1], s[2], s[3], sr };
            const float de[6] = { dl, d[0], d[1], d[2], d[3], dr };

#pragma unroll
            for (int p = 0; p < 2; ++p) {
                const int j0 = 2 * p, j1 = 2 * p + 1;
                v2f id, sx, sy, lp;
                id.x = mm[j0]; id.y = mm[j1];
                sx.x = se[j0 + 2] - se[j0];            sx.y = se[j1 + 2] - se[j1];
                sy.x = fmaf(2.f, de[j0 + 1], de[j0] + de[j0 + 2]);
                sy.y = fmaf(2.f, de[j1 + 1], de[j1] + de[j1 + 2]);
                lp.x = fmaf(-16.f, mm[j0], fmaf(2.f, se[j0 + 1], se[j0] + se[j0 + 2]));
                lp.y = fmaf(-16.f, mm[j1], fmaf(2.f, se[j1 + 1], se[j1] + se[j1 + 2]));
                xcv[ch][p] = id;
#pragma unroll
                for (int o = 0; o < HID; ++o) {
                    const float* w1r = w1w + o * 16 + ch * 4;   // scalar (K$) loads
                    v2f a = hpre[o][p];
                    a = __builtin_elementwise_fma(id, splat(w1r[0]), a);
                    a = __builtin_elementwise_fma(sx, splat(w1r[1]), a);
                    a = __builtin_elementwise_fma(sy, splat(w1r[2]), a);
                    a = __builtin_elementwise_fma(lp, splat(w1r[3]), a);
                    hpre[o][p] = a;
                }
            }
        }

#pragma unroll
        for (int o = 0; o < HID; ++o) {
            hpre[o][0] = __builtin_elementwise_max(hpre[o][0], splat(0.f));
            hpre[o][1] = __builtin_elementwise_max(hpre[o][1], splat(0.f));
        }

        v2f m0, m1;
        m0.x = floorf(nz.x + 0.5f); m0.y = floorf(nz.y + 0.5f);
        m1.x = floorf(nz.z + 0.5f); m1.y = floorf(nz.w + 0.5f);

#pragma unroll
        for (int ch = 0; ch < CH; ++ch) {
            v2f d0 = splat(0.f), d1 = splat(0.f);
#pragma unroll
            for (int o = 0; o < HID; ++o) {
                const v2f wv2 = splat(w2w[ch * HID + o]);   // scalar (K$) load
                d0 = __builtin_elementwise_fma(hpre[o][0], wv2, d0);
                d1 = __builtin_elementwise_fma(hpre[o][1], wv2, d1);
            }
            float4 ov;
            ov.x = fmaf(d0.x, m0.x, xcv[ch][0].x);
            ov.y = fmaf(d0.y, m0.y, xcv[ch][0].y);
            ov.z = fmaf(d1.x, m1.x, xcv[ch][1].x);
            ov.w = fmaf(d1.y, m1.y, xcv[ch][1].y);
            *(float4*)&out[((size_t)(b * CH + ch) * H + r) * W + w0] = ov;
        }

        nz = nz_next;
    }
}
} // namespace

extern "C" void kernel_launch(void* const* d_in, const int* in_sizes, int n_in,
                              void* d_out, int out_size, void* d_ws, size_t ws_size,
                              hipStream_t stream) {
    const float* x     = (const float*)d_in[0];
    const float* w1w   = (const float*)d_in[1];
    const float* w1b   = (const float*)d_in[2];
    const float* w2w   = (const float*)d_in[3];
    const float* noise = (const float*)d_in[4];
    float* out = (float*)d_out;

    const int blocks = B * (H / STRIP);   // 512 = 2 blocks/CU, all resident
    ca_kernel<<<blocks, 256, 0, stream>>>(x, w1w, w1b, w2w, noise, out);
}

// Round 10
// 37.660 us; speedup vs baseline: 1.4872x; 1.4872x over previous
//
#include <hip/hip_runtime.h>
#include <math.h>

namespace {
constexpr int B = 16, CH = 4, H = 512, W = 512, HID = 8;
constexpr int STRIP  = 8;            // rows per block
constexpr int SLOT_F = CH * W;       // one full row, all channels = 8 KB
constexpr int NSLOT  = 5;            // 40 KB ring -> 4 blocks/CU (160 KiB exact)

// Block = 512 thr = 8 waves = one row, 1 px/thread (thread == column).
// 4 blocks/CU x 512 thr = 2048 = CU max; grid 1024 = exactly 4/CU resident.
// Ring prefetched 3 rows ahead with counted vmcnt (never drained mid-loop).
// Full-row slots make the W-wrap a simple &511 on LDS reads (2-way, free).
__global__ __launch_bounds__(512) void ca_kernel(
    const float* __restrict__ x,      // [16,4,512,512]
    const float* __restrict__ w1w,    // [8,16]
    const float* __restrict__ w1b,    // [8]
    const float* __restrict__ w2w,    // [4,8]
    const float* __restrict__ noise,  // [16,1,512,512]
    float* __restrict__ out)          // [16,4,512,512]
{
    __shared__ float smem[NSLOT * SLOT_F];

    const int blk  = blockIdx.x;             // 1024 blocks
    const int b    = blk >> 6;               // image
    const int hs   = (blk & 63) * STRIP;     // strip start row
    const int tid  = threadIdx.x;            // 0..511 == column
    const int wv   = tid >> 6;               // wave 0..7
    const int lane = tid & 63;
    const int cm   = (tid + W - 1) & (W - 1);
    const int cp   = (tid + 1) & (W - 1);

    const float* xb = x + (size_t)b * CH * H * W;
    const int dch   = wv >> 1;               // DMA: wave -> (channel, half-row)
    const int dhalf = wv & 1;

    // stage one full row (4ch, 8KB): each of 8 waves one 1KB chunk
    auto dma = [&](int q) {
        const int row  = q & (H - 1);
        const int slot = (q - hs + 1) % NSLOT;          // compile-time after unroll
        const float* g = xb + ((size_t)dch * H + row) * W + dhalf * 256 + lane * 4;
        const float* l = &smem[slot * SLOT_F + dch * W + dhalf * 256]; // wave-uniform
        __builtin_amdgcn_global_load_lds(
            (const __attribute__((address_space(1))) void*)g,
            (__attribute__((address_space(3))) void*)l, 16, 0, 0);
    };
#define FENCE asm volatile("" ::: "memory")

    // prologue (VMEM order pinned by fences): dma hs-1..hs+1 | dma hs+2 | noise
    dma(hs - 1); dma(hs); dma(hs + 1); FENCE;
    dma(hs + 2); FENCE;
    const float* nb = noise + (size_t)b * H * W;
    float nz = nb[(size_t)hs * W + tid]; FENCE;

#pragma unroll
    for (int i = 0; i < STRIP; ++i) {
        // entry wait: this wave's dma chunk of row r+1 (issued 2 steps back)
        // has landed; barrier then propagates all waves' chunks.
        // Counts derived per-wave in-order: step VMEM = [dma][noise][4 stores].
        if      (i == 0) asm volatile("s_waitcnt vmcnt(2)"  ::: "memory");
        else if (i == 1) asm volatile("s_waitcnt vmcnt(7)"  ::: "memory");
        else if (i == 7) asm volatile("s_waitcnt vmcnt(10)" ::: "memory");
        else             asm volatile("s_waitcnt vmcnt(11)" ::: "memory");
        __builtin_amdgcn_s_barrier();

        if (i <= 5) dma(hs + i + 3);         // 3 rows ahead; slot (i+4)%5 is free
        FENCE;
        float nz_next = 0.f;
        if (i <= 6) nz_next = nb[(size_t)((hs + i + 1) & (H - 1)) * W + tid];
        FENCE;

        const int r  = hs + i;
        const int sT = i % NSLOT, sM = (i + 1) % NSLOT, sB = (i + 2) % NSLOT;

        float hpre[HID];
#pragma unroll
        for (int o = 0; o < HID; ++o) hpre[o] = w1b[o];   // scalar (K$) loads
        float xc[CH];

#pragma unroll
        for (int ch = 0; ch < CH; ++ch) {
            const float* T  = &smem[sT * SLOT_F + ch * W];
            const float* M  = &smem[sM * SLOT_F + ch * W];
            const float* Bt = &smem[sB * SLOT_F + ch * W];
            // 9 ds_read_b32, stride-1 lanes -> 2-way bank aliasing (free)
            const float tl = T[cm],  tc = T[tid],  tr = T[cp];
            const float ml = M[cm],  mc = M[tid],  mr = M[cp];
            const float bl = Bt[cm], bc = Bt[tid], br = Bt[cp];

            const float sl_ = fmaf(2.f, ml, tl + bl);
            const float sc_ = fmaf(2.f, mc, tc + bc);
            const float sr_ = fmaf(2.f, mr, tr + br);
            const float dl_ = bl - tl, dc_ = bc - tc, dr_ = br - tr;

            const float id = mc;
            const float sx = sr_ - sl_;
            const float sy = fmaf(2.f, dc_, dl_ + dr_);
            const float lp = fmaf(-16.f, mc, fmaf(2.f, sc_, sl_ + sr_));
            xc[ch] = mc;
#pragma unroll
            for (int o = 0; o < HID; ++o) {
                const float* w1r = w1w + o * 16 + ch * 4;   // scalar (K$) loads
                hpre[o] = fmaf(id, w1r[0],
                          fmaf(sx, w1r[1],
                          fmaf(sy, w1r[2],
                          fmaf(lp, w1r[3], hpre[o]))));
            }
        }

#pragma unroll
        for (int o = 0; o < HID; ++o) hpre[o] = fmaxf(hpre[o], 0.f);

        const float mk = floorf(nz + 0.5f);   // exact np semantics

#pragma unroll
        for (int ch = 0; ch < CH; ++ch) {
            float dd = 0.f;
#pragma unroll
            for (int o = 0; o < HID; ++o)
                dd = fmaf(hpre[o], w2w[ch * HID + o], dd);
            out[((size_t)(b * CH + ch) * H + r) * W + tid] = fmaf(dd, mk, xc[ch]);
        }

        nz = nz_next;
    }
#undef FENCE
}
} // namespace

extern "C" void kernel_launch(void* const* d_in, const int* in_sizes, int n_in,
                              void* d_out, int out_size, void* d_ws, size_t ws_size,
                              hipStream_t stream) {
    const float* x     = (const float*)d_in[0];
    const float* w1w   = (const float*)d_in[1];
    const float* w1b   = (const float*)d_in[2];
    const float* w2w   = (const float*)d_in[3];
    const float* noise = (const float*)d_in[4];
    float* out = (float*)d_out;

    const int blocks = B * (H / STRIP);   // 1024 = exactly 4 blocks/CU
    ca_kernel<<<blocks, 512, 0, stream>>>(x, w1w, w1b, w2w, noise, out);
}